// Round 8
// baseline (31.323 us; speedup 1.0000x reference)
//
#include <hip/hip_runtime.h>

#define N_NEUR 4096
#define T_STEPS 2048
#define DT 0.001f
#define TAU 10.0f
#define V_TH 100.0f
#define V_R -100.0f
#define DECAY (1.0f - DT / TAU)   // 0.9999f

#define SEG 16                    // time steps per prefix sub-segment
#define NSEG (T_STEPS / SEG)      // 128 sub-segments
#define BETA (DT * (float)SEG)    // 0.016 — per-segment bootstrap constant
#define NF4 (N_NEUR / 4)          // 1024 float4 columns
#define STRIPES 8                 // column stripes of 128 float4 each
#define PRE_B (NSEG * STRIPES)    // 1024 blocks

// ---------------------------------------------------------------------------
// Spike-impossibility proof (segment-wise bootstrap, per neuron):
// While no spike has occurred anywhere, exactly:
//   u_t = u0 + DT*S_t + DT*sum_{j<t} u_j^2 + (decay-sum of s0, |.| <= TAU|s0|)
// Per sub-segment g (16 steps): K_g = |u0| + TAU|s0| + eps + DT*max_t|S_t| + c_g,
// M_g = 1.5*K_g. If (checked in fp) M_g >= K_g + BETA*M_g^2, then |u_t| <= M_g
// throughout segment g by induction; c_{g+1} = c_g + BETA*M_g^2. If also
// M_g < 50 (half of v_th, ~100x above actual dynamics) for all g,i -> no spike
// can ever fire -> s is pure decay -> out[t] = s0*DECAY^(t+1).
// Any failed / NaN check falls to the exact sequential simulator.
// ---------------------------------------------------------------------------

// K1 (1024 blocks x 128): fused x-prefix-stats + out-writer.
// Block b: subseg ss=b>>3 (rows ss*16..+16), stripe st=b&7 (128 float4 cols).
// s0 load first, then 16 x-loads breadth-first, then the out-tile stores
// (depend only on s0 -> issue under x-load latency), then prefix chains.
// 128-thr blocks at 4 waves/EU give ~8 resident blocks/CU + 4x turnover so
// load-phases and compute/store-phases of different blocks overlap.
__global__ __launch_bounds__(128, 4) void k_pre(const float* __restrict__ x,
                                                const float* __restrict__ s0,
                                                float* __restrict__ out,
                                                float* __restrict__ seg_sum,
                                                float* __restrict__ seg_mm) {
    const int b = (int)blockIdx.x;
    const int tid = (int)threadIdx.x;
    const int ss = b >> 3;
    const int st = b & 7;
    const int f4c = st * 128 + tid;
    const int row0 = ss * SEG;

    // s0 first (oldest outstanding load)
    const float4 sv = ((const float4*)s0)[f4c];

    // issue all 16 x loads
    const float4* xp = (const float4*)x + (size_t)row0 * NF4 + f4c;
    float4 L[SEG];
    #pragma unroll
    for (int k = 0; k < SEG; ++k) L[k] = xp[(size_t)k * NF4];

    // out tile: needs only sv -> issues under x-load latency
    float scale = powf(DECAY, (float)(row0 + 1));
    float4* op = (float4*)out + (size_t)row0 * NF4 + f4c;
    #pragma unroll
    for (int k = 0; k < SEG; ++k) {
        float4 v = {sv.x * scale, sv.y * scale, sv.z * scale, sv.w * scale};
        op[(size_t)k * NF4] = v;
        scale *= DECAY;
    }

    // prefix chains over the 16 rows
    float4 run = {0.f, 0.f, 0.f, 0.f};
    float4 mx  = {0.f, 0.f, 0.f, 0.f};
    float4 mn  = {0.f, 0.f, 0.f, 0.f};
    #pragma unroll
    for (int k = 0; k < SEG; ++k) {
        run.x += L[k].x; mx.x = fmaxf(mx.x, run.x); mn.x = fminf(mn.x, run.x);
        run.y += L[k].y; mx.y = fmaxf(mx.y, run.y); mn.y = fminf(mn.y, run.y);
        run.z += L[k].z; mx.z = fmaxf(mx.z, run.z); mn.z = fminf(mn.z, run.z);
        run.w += L[k].w; mx.w = fmaxf(mx.w, run.w); mn.w = fminf(mn.w, run.w);
    }
    ((float4*)seg_sum)[(size_t)ss * NF4 + f4c] = run;
    // packed layout: mm[g][2*i] = mx_i, mm[g][2*i+1] = mn_i
    float4 a = {mx.x, mn.x, mx.y, mn.y};
    float4 c = {mx.z, mn.z, mx.w, mn.w};
    float4* mm4 = (float4*)seg_mm + (size_t)ss * (N_NEUR / 2) + (size_t)f4c * 2;
    mm4[0] = a;
    mm4[1] = c;
}

// K2 (32 blocks x 128): per-neuron bootstrap chain over 128 sub-segments.
// Breadth-first CSEG=32 chunks (4 iterations); one global bad word.
#define CSEG 32
__global__ __launch_bounds__(128, 2) void k_combine(const float* __restrict__ u0,
                                                    const float* __restrict__ s0,
                                                    const float* __restrict__ seg_sum,
                                                    const float* __restrict__ seg_mm,
                                                    int* __restrict__ bad_word) {
    const int tid = (int)threadIdx.x;
    const int i = (int)blockIdx.x * 128 + tid;
    if (blockIdx.x == 0 && tid == 0) *bad_word = 0;   // racy-but-safe: see below
    // NOTE: the init above races with other blocks' atomicOr only if they set
    // bad=1 concurrently; to be safe we instead initialize via a dedicated
    // lane writing BEFORE any check... simplest correct scheme: bad_word is
    // set by atomicOr only; k_slow treats (word & NON_INIT_MASK). To avoid
    // subtlety entirely we use a two-word scheme: blocks atomicAdd their bad
    // flag into word[blockIdx&1]+... -- overkill. We simply pre-clear both
    // words here guarded by __threadfence + the fact that clearing happens
    // in every block before its own atomicOr, and ORs are idempotent:
    // a stale clear cannot erase another block's OR because clears happen
    // only before this block's first check completes... which is NOT provable.
    // => Robust fix: each block writes its verdict to its own slot.
    const float base_term = fabsf(u0[i]) + TAU * fabsf(s0[i]) + 1e-3f;
    const float2* mm2 = (const float2*)seg_mm;

    bool bad = false;
    float base = 0.f;     // running prefix sum at segment start
    float c = 0.f;        // accumulated quadratic bound DT*sum u^2
    #pragma unroll 1
    for (int c0 = 0; c0 < NSEG; c0 += CSEG) {
        float S[CSEG];
        float2 MM[CSEG];
        #pragma unroll
        for (int k = 0; k < CSEG; ++k) {
            S[k]  = seg_sum[(size_t)(c0 + k) * N_NEUR + i];
            MM[k] = mm2[(size_t)(c0 + k) * N_NEUR + i];
        }
        #pragma unroll
        for (int k = 0; k < CSEG; ++k) {
            const float mxv = base + MM[k].x;
            const float mnv = base + MM[k].y;
            const float P = fmaxf(mxv, -mnv);      // max |prefix| in segment
            const float K = base_term + DT * P + c;
            const float M = 1.5f * K;
            bad |= !(M >= K + BETA * M * M);       // bootstrap check (NaN-safe)
            bad |= !(M < 50.0f);                   // spike margin check
            c += BETA * M * M;
            base += S[k];
        }
    }
    // per-block verdict slot (no init/OR race): slot = 1 + blockIdx
    const unsigned long long anyb = __ballot(bad);
    __syncthreads();                                // order ballots per wave
    if (tid == 0 || tid == 64) {
        // two waves: wave-0 lane0 and wave-1 lane0 both write; OR via atomic
        atomicOr(bad_word + 1 + blockIdx.x, (anyb != 0ull) ? 1 : 0);
    }
}

// K3 (1 block x 1024): reduce 32 verdict slots; fast-exit, else exact sim.
__global__ __launch_bounds__(1024) void k_slow(const float* __restrict__ x,
                                               const float* __restrict__ W,
                                               const float* __restrict__ u0,
                                               const float* __restrict__ s0,
                                               float* __restrict__ out,
                                               const int* __restrict__ bad_word) {
    __shared__ int any;
    const int tid = (int)threadIdx.x;
    if (tid == 0) any = 0;
    __syncthreads();
    if (tid < 32 && bad_word[1 + tid] != 0) any = 1;
    __syncthreads();
    if (any == 0) return;                // expected path: fast exit

    __shared__ float u[N_NEUR];
    __shared__ float s[N_NEUR];
    __shared__ int list[N_NEUR];
    __shared__ int cnt;
    for (int m = tid; m < N_NEUR; m += 1024) { u[m] = u0[m]; s[m] = s0[m]; }
    if (tid == 0) cnt = 0;
    __syncthreads();
    for (int t = 0; t < T_STEPS; ++t) {
        #pragma unroll
        for (int q = 0; q < 4; ++q) {
            const int i = tid + q * 1024;
            const float ui = u[i];
            const bool spk = ui >= V_TH;
            float un = ui + DT * (ui * ui + x[(size_t)t * N_NEUR + i] + s[i]);
            if (spk) {
                int p = atomicAdd(&cnt, 1);
                list[p] = i;
                un = V_R;
            }
            u[i] = un;
        }
        __syncthreads();
        const int k = cnt;
        #pragma unroll
        for (int q = 0; q < 4; ++q) {
            const int i = tid + q * 1024;
            float acc = 0.f;
            for (int m = 0; m < k; ++m) acc += W[(size_t)i * N_NEUR + list[m]];
            const float sn = s[i] * DECAY + acc;
            s[i] = sn;
            out[(size_t)t * N_NEUR + i] = sn;
        }
        __syncthreads();
        if (tid == 0) cnt = 0;
        __syncthreads();
    }
}

// K0 (1 block): clear the 33 verdict words (d_ws poisoned, never re-zeroed).
__global__ void k_clear(int* bad_word) {
    if (threadIdx.x < 33) bad_word[threadIdx.x] = 0;
}

// ---------------------------------------------------------------------------
// Fallback path (round-3 proven) if ws is too small for seg arrays.
// ---------------------------------------------------------------------------
#define NSCAN 64
#define CH 64
#define NCH (T_STEPS / CH)

__global__ __launch_bounds__(64, 1) void k_scan_fb(const float* __restrict__ x,
                                                   const float* __restrict__ u0,
                                                   const float* __restrict__ s0,
                                                   float* __restrict__ out,
                                                   int* __restrict__ flags) {
    const int b = (int)blockIdx.x;
    const int tid = (int)threadIdx.x;
    if (b >= NSCAN) {
        const int t = b - NSCAN;
        const float scale = powf(DECAY, (float)(t + 1));
        const float4* s4 = (const float4*)s0;
        float4* o4 = (float4*)out + (size_t)t * NF4;
        #pragma unroll
        for (int p = 0; p < 16; ++p) {
            const int c = p * 64 + tid;
            float4 v = s4[c];
            v.x *= scale; v.y *= scale; v.z *= scale; v.w *= scale;
            o4[c] = v;
        }
        return;
    }
    const int i = b * 64 + tid;
    const float* xp = x + i;
    float uu = u0[i], ss = s0[i], um = uu;
    float A[CH], B[CH], C[CH];
    auto loadch = [&](float (&dst)[CH], int ck) {
        const float* p = xp + (size_t)ck * CH * N_NEUR;
        #pragma unroll
        for (int k = 0; k < CH; ++k) dst[k] = p[(size_t)k * N_NEUR];
    };
    auto compch = [&](const float (&src)[CH]) {
        #pragma unroll
        for (int k = 0; k < CH; ++k) {
            um = fmaxf(um, uu);
            uu = fmaf(DT, fmaf(uu, uu, src[k] + ss), uu);
            ss *= DECAY;
        }
    };
    loadch(A, 0); loadch(B, 1);
    #pragma unroll 1
    for (int c = 0; c < NCH - 2; c += 3) {
        loadch(C, c + 2); compch(A);
        loadch(A, c + 3); compch(B);
        loadch(B, c + 4); compch(C);
    }
    compch(A); compch(B);
    const unsigned long long anyb = __ballot(um >= 50.0f);
    if (tid == 0) flags[b] = (anyb != 0ull) ? 1 : 0;
}

__global__ __launch_bounds__(1024) void k_slow_fb(const float* __restrict__ x,
                                                  const float* __restrict__ W,
                                                  const float* __restrict__ u0,
                                                  const float* __restrict__ s0,
                                                  float* __restrict__ out,
                                                  const int* __restrict__ flags) {
    __shared__ int any;
    const int tid = (int)threadIdx.x;
    if (tid == 0) any = 0;
    __syncthreads();
    if (tid < NSCAN && flags[tid] != 0) any = 1;
    __syncthreads();
    if (any == 0) return;
    __shared__ float u[N_NEUR];
    __shared__ float s[N_NEUR];
    __shared__ int list[N_NEUR];
    __shared__ int cnt;
    for (int m = tid; m < N_NEUR; m += 1024) { u[m] = u0[m]; s[m] = s0[m]; }
    if (tid == 0) cnt = 0;
    __syncthreads();
    for (int t = 0; t < T_STEPS; ++t) {
        #pragma unroll
        for (int q = 0; q < 4; ++q) {
            const int i = tid + q * 1024;
            const float ui = u[i];
            const bool spk = ui >= V_TH;
            float un = ui + DT * (ui * ui + x[(size_t)t * N_NEUR + i] + s[i]);
            if (spk) { int p = atomicAdd(&cnt, 1); list[p] = i; un = V_R; }
            u[i] = un;
        }
        __syncthreads();
        const int k = cnt;
        #pragma unroll
        for (int q = 0; q < 4; ++q) {
            const int i = tid + q * 1024;
            float acc = 0.f;
            for (int m = 0; m < k; ++m) acc += W[(size_t)i * N_NEUR + list[m]];
            const float sn = s[i] * DECAY + acc;
            s[i] = sn;
            out[(size_t)t * N_NEUR + i] = sn;
        }
        __syncthreads();
        if (tid == 0) cnt = 0;
        __syncthreads();
    }
}

// ---------------------------------------------------------------------------
extern "C" void kernel_launch(void* const* d_in, const int* in_sizes, int n_in,
                              void* d_out, int out_size, void* d_ws, size_t ws_size,
                              hipStream_t stream) {
    const float* x  = (const float*)d_in[0];   // [T, N]
    const float* W  = (const float*)d_in[1];   // [N, N]
    const float* u0 = (const float*)d_in[2];   // [N]
    const float* s0 = (const float*)d_in[3];   // [N]
    float* out = (float*)d_out;                // [T, N]

    const size_t sum_elems = (size_t)NSEG * N_NEUR;        // 512K floats (2 MB)
    const size_t mm_elems  = (size_t)NSEG * N_NEUR * 2;    // 1M floats (4 MB)
    if (ws_size >= (sum_elems + mm_elems) * sizeof(float) + 64 * sizeof(int)) {
        float* seg_sum = (float*)d_ws;
        float* seg_mm  = seg_sum + sum_elems;
        int* bad_word  = (int*)(seg_mm + mm_elems);        // [0]=unused,[1..32]=verdicts
        k_clear<<<1, 64, 0, stream>>>(bad_word);
        k_pre<<<PRE_B, 128, 0, stream>>>(x, s0, out, seg_sum, seg_mm);
        k_combine<<<32, 128, 0, stream>>>(u0, s0, seg_sum, seg_mm, bad_word);
        k_slow<<<1, 1024, 0, stream>>>(x, W, u0, s0, out, bad_word);
    } else {
        int* flags = (int*)d_ws;
        k_scan_fb<<<NSCAN + T_STEPS, 64, 0, stream>>>(x, u0, s0, out, flags);
        k_slow_fb<<<1, 1024, 0, stream>>>(x, W, u0, s0, out, flags);
    }
}

// Round 10
// 26.830 us; speedup vs baseline: 1.1675x; 1.1675x over previous
//
#include <hip/hip_runtime.h>

#define N_NEUR 4096
#define T_STEPS 2048
#define DT 0.001f
#define TAU 10.0f
#define V_TH 100.0f
#define V_R -100.0f
#define DECAY (1.0f - DT / TAU)   // 0.9999f

#define SEG 16                    // time steps per prefix sub-segment
#define NSEG (T_STEPS / SEG)      // 128 sub-segments
#define BETA (DT * (float)SEG)    // 0.016 — per-segment bootstrap constant
#define NF4 (N_NEUR / 4)          // 1024 float4 columns
#define PRE_B (NSEG * 4)          // 512 blocks (128 subsegs x 4 stripes of 256 cols)

typedef float f4 __attribute__((ext_vector_type(4)));   // native vec for NT builtins

// ---------------------------------------------------------------------------
// Spike-impossibility proof (segment-wise bootstrap, per neuron):
// While no spike has occurred anywhere, exactly:
//   u_t = u0 + DT*S_t + DT*sum_{j<t} u_j^2 + (decay-sum of s0, |.| <= TAU|s0|)
// Per sub-segment g (16 steps), with base = S at segment start and P_g =
// max in-segment |S_t - base|:  K_g = |u0| + TAU|s0| + eps + DT*(|base|+P_g) + c_g,
// M_g = 1.5*K_g. If (checked in fp) M_g >= K_g + BETA*M_g^2 then |u_t| <= M_g
// throughout segment g by induction; c_{g+1} = c_g + BETA*M_g^2. If also
// M_g < 50 (half of v_th, ~100x above actual dynamics) for all g,i -> no spike
// can ever fire -> s is pure decay -> out[t] = s0*DECAY^(t+1).
// Any failed / NaN check falls to the exact sequential simulator.
// ---------------------------------------------------------------------------

// K1 (512 blocks x 256): fused x-prefix-stats + out-writer.
// Block b: subseg ss=b>>2 (rows ss*16..+16), stripe st=b&3 (256 float4 cols).
// Order: s0 load first, then 16 x-loads breadth-first (nontemporal), then the
// out-tile stores (depend only on s0 -> issue under x-load latency, NT), then
// prefix chains + seg store {sum, P} (NT).
__global__ __launch_bounds__(256, 2) void k_pre(const float* __restrict__ x,
                                                const float* __restrict__ s0,
                                                float* __restrict__ out,
                                                float* __restrict__ seg) {
    const int b = (int)blockIdx.x;
    const int tid = (int)threadIdx.x;
    const int ss = b >> 2;
    const int st = b & 3;
    const int f4c = st * 256 + tid;
    const int row0 = ss * SEG;

    // s0 first (oldest outstanding load)
    const f4 sv = ((const f4*)s0)[f4c];

    // issue all 16 x loads (streaming)
    const f4* xp = (const f4*)x + (size_t)row0 * NF4 + f4c;
    f4 L[SEG];
    #pragma unroll
    for (int k = 0; k < SEG; ++k)
        L[k] = __builtin_nontemporal_load(&xp[(size_t)k * NF4]);

    // out tile: needs only sv -> issues under x-load latency
    float scale = powf(DECAY, (float)(row0 + 1));
    f4* op = (f4*)out + (size_t)row0 * NF4 + f4c;
    #pragma unroll
    for (int k = 0; k < SEG; ++k) {
        f4 v = sv * scale;
        __builtin_nontemporal_store(v, &op[(size_t)k * NF4]);
        scale *= DECAY;
    }

    // prefix chains over the 16 rows
    f4 run = {0.f, 0.f, 0.f, 0.f};
    f4 mx  = {0.f, 0.f, 0.f, 0.f};
    f4 mn  = {0.f, 0.f, 0.f, 0.f};
    #pragma unroll
    for (int k = 0; k < SEG; ++k) {
        run.x += L[k].x; mx.x = fmaxf(mx.x, run.x); mn.x = fminf(mn.x, run.x);
        run.y += L[k].y; mx.y = fmaxf(mx.y, run.y); mn.y = fminf(mn.y, run.y);
        run.z += L[k].z; mx.z = fmaxf(mx.z, run.z); mn.z = fminf(mn.z, run.z);
        run.w += L[k].w; mx.w = fmaxf(mx.w, run.w); mn.w = fminf(mn.w, run.w);
    }
    // packed per-neuron float2 {sum, P}: seg2[g*N + i]
    const f4 a = {run.x, fmaxf(mx.x, -mn.x), run.y, fmaxf(mx.y, -mn.y)};
    const f4 c = {run.z, fmaxf(mx.z, -mn.z), run.w, fmaxf(mx.w, -mn.w)};
    f4* sp = (f4*)seg + (size_t)ss * (N_NEUR / 2) + (size_t)f4c * 2;
    __builtin_nontemporal_store(a, &sp[0]);
    __builtin_nontemporal_store(c, &sp[1]);
}

// K2 (32 blocks x 128): per-neuron bootstrap chain over 128 sub-segments.
// Breadth-first CSEG=32 chunks; per-block verdict via plain store (every slot
// written every run -> no init kernel, no atomic/init race).
#define CSEG 32
__global__ __launch_bounds__(128, 2) void k_combine(const float* __restrict__ u0,
                                                    const float* __restrict__ s0,
                                                    const float* __restrict__ seg,
                                                    int* __restrict__ verd) {
    __shared__ int blkbad;
    const int tid = (int)threadIdx.x;
    if (tid == 0) blkbad = 0;
    __syncthreads();

    const int i = (int)blockIdx.x * 128 + tid;
    const float base_term = fabsf(u0[i]) + TAU * fabsf(s0[i]) + 1e-3f;
    const float2* seg2 = (const float2*)seg;

    bool bad = false;
    float base = 0.f;     // running prefix sum at segment start
    float c = 0.f;        // accumulated quadratic bound DT*sum u^2
    #pragma unroll 1
    for (int c0 = 0; c0 < NSEG; c0 += CSEG) {
        float2 SP[CSEG];
        #pragma unroll
        for (int k = 0; k < CSEG; ++k)
            SP[k] = seg2[(size_t)(c0 + k) * N_NEUR + i];
        #pragma unroll
        for (int k = 0; k < CSEG; ++k) {
            const float K = base_term + DT * (fabsf(base) + SP[k].y) + c;
            const float M = 1.5f * K;
            bad |= !(M >= K + BETA * M * M);       // bootstrap check (NaN-safe)
            bad |= !(M < 50.0f);                   // spike margin check
            c += BETA * M * M;
            base += SP[k].x;
        }
    }
    if (bad) atomicOr(&blkbad, 1);                 // LDS atomic
    __syncthreads();
    if (tid == 0) verd[blockIdx.x] = blkbad;       // plain store, no init needed
}

// K3 (1 block x 1024): reduce 32 verdict slots; fast-exit, else exact sim.
__global__ __launch_bounds__(1024) void k_slow(const float* __restrict__ x,
                                               const float* __restrict__ W,
                                               const float* __restrict__ u0,
                                               const float* __restrict__ s0,
                                               float* __restrict__ out,
                                               const int* __restrict__ verd) {
    __shared__ int any;
    const int tid = (int)threadIdx.x;
    if (tid == 0) any = 0;
    __syncthreads();
    if (tid < 32 && verd[tid] != 0) any = 1;
    __syncthreads();
    if (any == 0) return;                // expected path: fast exit

    __shared__ float u[N_NEUR];
    __shared__ float s[N_NEUR];
    __shared__ int list[N_NEUR];
    __shared__ int cnt;
    for (int m = tid; m < N_NEUR; m += 1024) { u[m] = u0[m]; s[m] = s0[m]; }
    if (tid == 0) cnt = 0;
    __syncthreads();
    for (int t = 0; t < T_STEPS; ++t) {
        #pragma unroll
        for (int q = 0; q < 4; ++q) {
            const int i = tid + q * 1024;
            const float ui = u[i];
            const bool spk = ui >= V_TH;
            float un = ui + DT * (ui * ui + x[(size_t)t * N_NEUR + i] + s[i]);
            if (spk) {
                int p = atomicAdd(&cnt, 1);
                list[p] = i;
                un = V_R;
            }
            u[i] = un;
        }
        __syncthreads();
        const int k = cnt;
        #pragma unroll
        for (int q = 0; q < 4; ++q) {
            const int i = tid + q * 1024;
            float acc = 0.f;
            for (int m = 0; m < k; ++m) acc += W[(size_t)i * N_NEUR + list[m]];
            const float sn = s[i] * DECAY + acc;
            s[i] = sn;
            out[(size_t)t * N_NEUR + i] = sn;
        }
        __syncthreads();
        if (tid == 0) cnt = 0;
        __syncthreads();
    }
}

// ---------------------------------------------------------------------------
// Fallback path (round-3 proven) if ws is too small for seg arrays.
// ---------------------------------------------------------------------------
#define NSCAN 64
#define CH 64
#define NCH (T_STEPS / CH)

__global__ __launch_bounds__(64, 1) void k_scan_fb(const float* __restrict__ x,
                                                   const float* __restrict__ u0,
                                                   const float* __restrict__ s0,
                                                   float* __restrict__ out,
                                                   int* __restrict__ flags) {
    const int b = (int)blockIdx.x;
    const int tid = (int)threadIdx.x;
    if (b >= NSCAN) {
        const int t = b - NSCAN;
        const float scale = powf(DECAY, (float)(t + 1));
        const float4* s4 = (const float4*)s0;
        float4* o4 = (float4*)out + (size_t)t * NF4;
        #pragma unroll
        for (int p = 0; p < 16; ++p) {
            const int c = p * 64 + tid;
            float4 v = s4[c];
            v.x *= scale; v.y *= scale; v.z *= scale; v.w *= scale;
            o4[c] = v;
        }
        return;
    }
    const int i = b * 64 + tid;
    const float* xp = x + i;
    float uu = u0[i], ss = s0[i], um = uu;
    float A[CH], B[CH], C[CH];
    auto loadch = [&](float (&dst)[CH], int ck) {
        const float* p = xp + (size_t)ck * CH * N_NEUR;
        #pragma unroll
        for (int k = 0; k < CH; ++k) dst[k] = p[(size_t)k * N_NEUR];
    };
    auto compch = [&](const float (&src)[CH]) {
        #pragma unroll
        for (int k = 0; k < CH; ++k) {
            um = fmaxf(um, uu);
            uu = fmaf(DT, fmaf(uu, uu, src[k] + ss), uu);
            ss *= DECAY;
        }
    };
    loadch(A, 0); loadch(B, 1);
    #pragma unroll 1
    for (int c = 0; c < NCH - 2; c += 3) {
        loadch(C, c + 2); compch(A);
        loadch(A, c + 3); compch(B);
        loadch(B, c + 4); compch(C);
    }
    compch(A); compch(B);
    const unsigned long long anyb = __ballot(um >= 50.0f);
    if (tid == 0) flags[b] = (anyb != 0ull) ? 1 : 0;
}

__global__ __launch_bounds__(1024) void k_slow_fb(const float* __restrict__ x,
                                                  const float* __restrict__ W,
                                                  const float* __restrict__ u0,
                                                  const float* __restrict__ s0,
                                                  float* __restrict__ out,
                                                  const int* __restrict__ flags) {
    __shared__ int any;
    const int tid = (int)threadIdx.x;
    if (tid == 0) any = 0;
    __syncthreads();
    if (tid < NSCAN && flags[tid] != 0) any = 1;
    __syncthreads();
    if (any == 0) return;
    __shared__ float u[N_NEUR];
    __shared__ float s[N_NEUR];
    __shared__ int list[N_NEUR];
    __shared__ int cnt;
    for (int m = tid; m < N_NEUR; m += 1024) { u[m] = u0[m]; s[m] = s0[m]; }
    if (tid == 0) cnt = 0;
    __syncthreads();
    for (int t = 0; t < T_STEPS; ++t) {
        #pragma unroll
        for (int q = 0; q < 4; ++q) {
            const int i = tid + q * 1024;
            const float ui = u[i];
            const bool spk = ui >= V_TH;
            float un = ui + DT * (ui * ui + x[(size_t)t * N_NEUR + i] + s[i]);
            if (spk) { int p = atomicAdd(&cnt, 1); list[p] = i; un = V_R; }
            u[i] = un;
        }
        __syncthreads();
        const int k = cnt;
        #pragma unroll
        for (int q = 0; q < 4; ++q) {
            const int i = tid + q * 1024;
            float acc = 0.f;
            for (int m = 0; m < k; ++m) acc += W[(size_t)i * N_NEUR + list[m]];
            const float sn = s[i] * DECAY + acc;
            s[i] = sn;
            out[(size_t)t * N_NEUR + i] = sn;
        }
        __syncthreads();
        if (tid == 0) cnt = 0;
        __syncthreads();
    }
}

// ---------------------------------------------------------------------------
extern "C" void kernel_launch(void* const* d_in, const int* in_sizes, int n_in,
                              void* d_out, int out_size, void* d_ws, size_t ws_size,
                              hipStream_t stream) {
    const float* x  = (const float*)d_in[0];   // [T, N]
    const float* W  = (const float*)d_in[1];   // [N, N]
    const float* u0 = (const float*)d_in[2];   // [N]
    const float* s0 = (const float*)d_in[3];   // [N]
    float* out = (float*)d_out;                // [T, N]

    const size_t seg_elems = (size_t)NSEG * N_NEUR * 2;    // 1M floats (4 MB)
    if (ws_size >= seg_elems * sizeof(float) + 32 * sizeof(int)) {
        float* seg = (float*)d_ws;
        int* verd  = (int*)(seg + seg_elems);              // 32 verdict slots
        k_pre<<<PRE_B, 256, 0, stream>>>(x, s0, out, seg);
        k_combine<<<32, 128, 0, stream>>>(u0, s0, seg, verd);
        k_slow<<<1, 1024, 0, stream>>>(x, W, u0, s0, out, verd);
    } else {
        int* flags = (int*)d_ws;
        k_scan_fb<<<NSCAN + T_STEPS, 64, 0, stream>>>(x, u0, s0, out, flags);
        k_slow_fb<<<1, 1024, 0, stream>>>(x, W, u0, s0, out, flags);
    }
}